// Round 2
// 282.946 us; speedup vs baseline: 1.0545x; 1.0545x over previous
//
#include <hip/hip_runtime.h>
#include <hip/hip_bf16.h>
#include <stdint.h>

#define B_ 4
#define T_ 512
#define H_ 32
#define N_ 64
#define D_ 2048
#define M_ (B_*T_)

typedef __attribute__((ext_vector_type(4))) float f32x4;
typedef __attribute__((ext_vector_type(8))) short short8;

// DPP butterfly add across 16-lane groups: pure VALU.
template <int CTRL>
__device__ __forceinline__ float dpp_add(float x) {
    int t = __builtin_amdgcn_mov_dpp(__float_as_int(x), CTRL, 0xF, 0xF, true);
    return x + __int_as_float(t);
}
__device__ __forceinline__ float bfly16(float x) {
    x = dpp_add<0xB1>(x);    // xor1
    x = dpp_add<0x4E>(x);    // xor2
    x = dpp_add<0x141>(x);   // xor4 row_half_mirror
    x = dpp_add<0x140>(x);   // xor8 row_mirror
    return x;
}

__device__ __forceinline__ void gld16(const float* g, float* l) {
    __builtin_amdgcn_global_load_lds(
        (const __attribute__((address_space(1))) unsigned int*)g,
        (__attribute__((address_space(3))) unsigned int*)l, 16, 0, 0);
}

// ---------------------------------------------------------------------------
// Kernel 1: precompute+pack streams into pk[bh][t][6][64]
// (streams: r,k,v,dec,kk,bb). Weight dequant moved into wkv_scan's grid
// (runs in the scan's latency shadow).
// ---------------------------------------------------------------------------
__global__ __launch_bounds__(256) void prep(
    const float* __restrict__ r, const float* __restrict__ w,
    const float* __restrict__ k, const float* __restrict__ v,
    const float* __restrict__ iclr, float* __restrict__ pk) {
    int g = blockIdx.x * 4 + (threadIdx.x >> 6);   // (b,t,h) flat index
    int lane = threadIdx.x & 63;
    int b = g >> 14;             // / (T*H)
    int t = (g >> 5) & (T_ - 1); // / H % T
    int h = g & 31;              // % H
    size_t si = (size_t)g * 64 + lane;
    size_t di = (((size_t)(b * H_ + h) * T_) + t) * 384 + lane;  // stream 0 chan
    float rv = r[si], wv = w[si], kv = k[si], vv = v[si], av = iclr[si];
    float d = expf(-expf(wv));
    float ss = kv * kv;
#pragma unroll
    for (int m = 1; m < 64; m <<= 1) ss += __shfl_xor(ss, m, 64);
    float kkv = kv * rsqrtf(ss + 1e-12f);
    float bbv = kkv * (1.f / (1.f + expf(-av)));
    pk[di          ] = rv;
    pk[di + 1 * 64 ] = kv;
    pk[di + 2 * 64 ] = vv;
    pk[di + 3 * 64 ] = d;
    pk[di + 4 * 64 ] = kkv;
    pk[di + 5 * 64 ] = bbv;
}

// ---------------------------------------------------------------------------
// Kernel 2: WKV-7 scan, packed-stream LDS ring, one-step-ahead register
// prefetch of the 6 stream fragments (R6: VGPR was 52 -> compiler issued
// ds_reads JIT, ~3-4 x 120cyc unhidden LDS latency per step).
// Pipeline: nxt = ldfrag(t+1) issued before compute(cur); the ~150cyc
// compute shadow covers the ds_read latency.
// vmcnt accounting: per group 6 refill DMAs + 4 y-stores. At i==3 the
// needed refill (issued end of g-1, slot (g+1)&1) has exactly 3 newer vm
// ops above it (stores i=0..2 of g) -> constant s_waitcnt vmcnt(3); holds
// for g==0 too (prologue slot1 DMAs are the 6 below the 3 stores).
// Blocks >= 2048: int32 -> bf16 weight dequant riding in the scan's shadow
// (wkv occupies only 8 of 32 wave slots/CU; dequant fills the rest).
// ---------------------------------------------------------------------------
struct Frag {
    f32x4 R, Kk, Dd, Aa, Bb;
    float v;
};

__device__ __forceinline__ Frag ldfrag(const float* rb, int jg, int row) {
    Frag f;
    f.R  = *(const f32x4*)(rb + 0 * 64 + jg * 4);
    f.Kk = *(const f32x4*)(rb + 1 * 64 + jg * 4);
    f.v  = rb[2 * 64 + row];
    f.Dd = *(const f32x4*)(rb + 3 * 64 + jg * 4);
    f.Aa = *(const f32x4*)(rb + 4 * 64 + jg * 4);
    f.Bb = *(const f32x4*)(rb + 5 * 64 + jg * 4);
    return f;
}

__global__ __launch_bounds__(64, 2) void wkv_scan(
    const float* __restrict__ pk, __hip_bfloat16* __restrict__ y,
    const int* __restrict__ q, __hip_bfloat16* __restrict__ o) {
    if (blockIdx.x >= 2048) {      // ---- weight dequant part ----
        int i = ((blockIdx.x - 2048) * 64 + (int)threadIdx.x) * 4;
        int4 qi = *(const int4*)(q + i);
        __hip_bfloat16 t[4];
        t[0] = __float2bfloat16((float)qi.x);
        t[1] = __float2bfloat16((float)qi.y);
        t[2] = __float2bfloat16((float)qi.z);
        t[3] = __float2bfloat16((float)qi.w);
        *(uint2*)(o + i) = *(uint2*)t;
        return;
    }
    const int bh = blockIdx.x & 127;
    const int wv = blockIdx.x >> 7;
    const int b = bh >> 5, h = bh & 31;
    const int lane = threadIdx.x;
    const int jg = lane & 15;
    const int rl = lane >> 4;
    const int row = wv * 4 + rl;

    __shared__ __align__(16) float ring[2 * 1536];   // 12 KB

    const float* src = pk + (size_t)bh * T_ * 384;

    // prologue: fill both superslots (12 DMAs outstanding)
#pragma unroll
    for (int gg = 0; gg < 2; ++gg) {
        const float* g0 = src + (size_t)gg * 1536 + lane * 4;
        float* l0 = &ring[gg * 1536];
#pragma unroll
        for (int c = 0; c < 6; ++c)
            gld16(g0 + c * 256, l0 + c * 256);
    }

    asm volatile("s_waitcnt vmcnt(6)" ::: "memory");  // slot0 landed
    Frag cur = ldfrag(&ring[0], jg, row);
    float S[4] = {0.f, 0.f, 0.f, 0.f};

    for (int g = 0; g < T_ / 4; ++g) {
        const float* rb0 = &ring[(g & 1) * 1536];
        const float* nb0 = &ring[((g + 1) & 1) * 1536];
#pragma unroll
        for (int i = 0; i < 4; ++i) {
            // issue next step's LDS reads before computing on cur
            Frag nxt;
            if (i < 3) {
                nxt = ldfrag(rb0 + (i + 1) * 384, jg, row);
            } else {
                asm volatile("s_waitcnt vmcnt(3)" ::: "memory");
                nxt = ldfrag(nb0, jg, row);
            }

            // sa = -(S_old . kk)
            float s01 = fmaf(S[1], cur.Aa[1], S[0] * cur.Aa[0]);
            float s23 = fmaf(S[3], cur.Aa[3], S[2] * cur.Aa[2]);
            const float sa = -bfly16(s01 + s23);

            // S = S*dec + sa*bb + v*k ;  y partial = S_new . r
            float t0 = fmaf(sa, cur.Bb[0], cur.v * cur.Kk[0]);
            S[0] = fmaf(S[0], cur.Dd[0], t0);
            float t1 = fmaf(sa, cur.Bb[1], cur.v * cur.Kk[1]);
            S[1] = fmaf(S[1], cur.Dd[1], t1);
            float y01 = fmaf(S[1], cur.R[1], S[0] * cur.R[0]);
            float t2 = fmaf(sa, cur.Bb[2], cur.v * cur.Kk[2]);
            S[2] = fmaf(S[2], cur.Dd[2], t2);
            float t3 = fmaf(sa, cur.Bb[3], cur.v * cur.Kk[3]);
            S[3] = fmaf(S[3], cur.Dd[3], t3);
            float y23 = fmaf(S[3], cur.R[3], S[2] * cur.R[2]);
            float ys = bfly16(y01 + y23);
            if (jg == 0)
                y[((size_t)b * T_ + (g * 4 + i)) * D_ + h * 64 + row] =
                    __float2bfloat16(ys);
            cur = nxt;
        }

        // refill this slot with group g+2 (clamped tail re-reads: harmless)
        asm volatile("" ::: "memory");
        int gp = g + 2; if (gp > T_ / 4 - 1) gp = T_ / 4 - 1;
        const float* g0 = src + (size_t)gp * 1536 + lane * 4;
        float* l0 = &ring[(g & 1) * 1536];
#pragma unroll
        for (int c = 0; c < 6; ++c)
            gld16(g0 + c * 256, l0 + c * 256);
    }
}

// ---------------------------------------------------------------------------
// Kernel 3: C[m,o] = scale[o] * sum_d Y[m,d] * Wq[o,d]  (B^T GEMM)
// 128x64 tile, BK=64, 4 waves (2x2 over 64x32 sub-tiles).
// R6: 128x128 gave 256 blocks = 1 block/CU -> every barrier+vmcnt(0) drain
// idled the whole CU. 128x64 -> 512 blocks = 2/CU so the co-resident block
// covers the drain. LDS 24KB, VGPR ~80 under the (256,2) budget.
// ---------------------------------------------------------------------------
__device__ __forceinline__ void gload_lds16(const __hip_bfloat16* g, ushort* l) {
    __builtin_amdgcn_global_load_lds(
        (const __attribute__((address_space(1))) unsigned int*)g,
        (__attribute__((address_space(3))) unsigned int*)l, 16, 0, 0);
}

__global__ __launch_bounds__(256, 2) void gemm_bt(
    const __hip_bfloat16* __restrict__ A,   // [M, K]
    const __hip_bfloat16* __restrict__ Bq,  // [N, K]
    const float* __restrict__ scale,        // [N]
    float* __restrict__ C) {                // [M, N]
    const int K = D_;
    __shared__ __align__(16) ushort As[128 * 64];   // 16 KB
    __shared__ __align__(16) ushort Bs[64 * 64];    //  8 KB

    const int tid = threadIdx.x;
    const int lane = tid & 63;
    const int wave = tid >> 6;
    const int wr = wave >> 1, wc = wave & 1;
    const int m0 = blockIdx.x * 128;
    const int n0 = blockIdx.y * 64;

    const int srow8 = lane >> 3;
    const int scol8 = (lane & 7) * 8;
    const int ml = lane & 15;
    const int kq = (lane >> 4) * 8;

    f32x4 acc[4][2] = {};

    for (int k0 = 0; k0 < K; k0 += 64) {
#pragma unroll
        for (int c = 0; c < 4; ++c) {
            int ra = wave * 32 + c * 8;
            gload_lds16(A + (size_t)(m0 + ra + srow8) * K + k0 + scol8,
                        &As[ra * 64]);
        }
#pragma unroll
        for (int c = 0; c < 2; ++c) {
            int rb = wave * 16 + c * 8;
            gload_lds16(Bq + (size_t)(n0 + rb + srow8) * K + k0 + scol8,
                        &Bs[rb * 64]);
        }
        __syncthreads();
#pragma unroll
        for (int ks = 0; ks < 2; ++ks) {
            short8 af[4], bf[2];
#pragma unroll
            for (int tm = 0; tm < 4; ++tm)
                af[tm] = *(const short8*)(&As[(wr * 64 + tm * 16 + ml) * 64 + ks * 32 + kq]);
#pragma unroll
            for (int tn = 0; tn < 2; ++tn)
                bf[tn] = *(const short8*)(&Bs[(wc * 32 + tn * 16 + ml) * 64 + ks * 32 + kq]);
#pragma unroll
            for (int tm = 0; tm < 4; ++tm)
#pragma unroll
                for (int tn = 0; tn < 2; ++tn)
                    acc[tm][tn] = __builtin_amdgcn_mfma_f32_16x16x32_bf16(
                        af[tm], bf[tn], acc[tm][tn], 0, 0, 0);
        }
        __syncthreads();
    }

#pragma unroll
    for (int tn = 0; tn < 2; ++tn) {
        int gn = n0 + wc * 32 + tn * 16 + ml;
        float sc = scale[gn];
#pragma unroll
        for (int tm = 0; tm < 4; ++tm) {
            int gm = m0 + wr * 64 + tm * 16 + (lane >> 4) * 4;
#pragma unroll
            for (int rg = 0; rg < 4; ++rg)
                C[(size_t)(gm + rg) * D_ + gn] = acc[tm][tn][rg] * sc;
        }
    }
}

// ---------------------------------------------------------------------------
extern "C" void kernel_launch(void* const* d_in, const int* in_sizes, int n_in,
                              void* d_out, int out_size, void* d_ws, size_t ws_size,
                              hipStream_t stream) {
    (void)in_sizes; (void)n_in; (void)out_size; (void)ws_size;
    const float* r  = (const float*)d_in[0];
    const float* w  = (const float*)d_in[1];
    const float* k  = (const float*)d_in[2];
    const float* v  = (const float*)d_in[3];
    const float* ic = (const float*)d_in[4];
    const int*   wq = (const int*)d_in[5];
    const float* sc = (const float*)d_in[6];
    float* out = (float*)d_out;

    // ws: yb 8.4MB | wb 8.4MB | pk (packed streams) 100.7MB  (~118 MB total)
    char* p = (char*)d_ws;
    __hip_bfloat16* yb = (__hip_bfloat16*)p;  p += (size_t)M_ * D_ * 2;
    __hip_bfloat16* wb = (__hip_bfloat16*)p;  p += (size_t)D_ * D_ * 2;
    float* pk = (float*)p;

    prep    <<<dim3(16384), dim3(256), 0, stream>>>(r, w, k, v, ic, pk);
    wkv_scan<<<dim3(2048 + 16384), dim3(64), 0, stream>>>(pk, yb, wq, wb);
    gemm_bt <<<dim3(M_ / 128, D_ / 64), dim3(256), 0, stream>>>(yb, wb, sc, out);
}